// Round 3
// baseline (113.067 us; speedup 1.0000x reference)
//
#include <hip/hip_runtime.h>
#include <hip/hip_bf16.h>
#include <math.h>

typedef __bf16 bf16;
typedef _Float16 f16;
typedef __attribute__((ext_vector_type(8))) __bf16 bf16x8;
typedef __attribute__((ext_vector_type(8))) _Float16 f16x8;
typedef __attribute__((ext_vector_type(4))) _Float16 f16x4;
typedef __attribute__((ext_vector_type(4))) float floatx4;

__device__ __forceinline__ void split8(floatx4 a0, floatx4 a1, bf16x8& hi, bf16x8& lo) {
#pragma unroll
    for (int t = 0; t < 4; t++) {
        float v0 = a0[t], v1 = a1[t];
        bf16 h0 = (bf16)v0, h1 = (bf16)v1;
        hi[t] = h0;     lo[t] = (bf16)(v0 - (float)h0);
        hi[t + 4] = h1; lo[t + 4] = (bf16)(v1 - (float)h1);
    }
}

// ---------------- projection: qkv = hs @ Wqkv^T + bqkv (fp32-accurate via bf16 hi/lo split) ----------------
// blocks 0..383: one 16x16 tile per wave -> q f16 [b*s][r], k f16 [b*l][r], vT f16 [b][p][l]
// blocks 384..447: Wc fp32 -> f16 copy (for the attn B-frag build)
__global__ __launch_bounds__(256, 4)
void proj_kernel(const float* __restrict__ hs, const float* __restrict__ Wq,
                 const float* __restrict__ bq, const float* __restrict__ Wc,
                 f16* __restrict__ q_ws, f16* __restrict__ k_ws,
                 f16* __restrict__ vT_ws, f16* __restrict__ Wc_ws)
{
    const int tid = threadIdx.x;
    if (blockIdx.x >= 384) {           // Wc fp32 -> f16
        const int base = (blockIdx.x - 384) * 1024 + tid * 4;
        floatx4 w = *(const floatx4*)(Wc + base);
        f16x4 h;
        h.x = (f16)w.x; h.y = (f16)w.y; h.z = (f16)w.z; h.w = (f16)w.w;
        *(f16x4*)(Wc_ws + base) = h;
        return;
    }
    const int wv = tid >> 6, lane = tid & 63;
    const int quad = lane >> 4, lcol = lane & 15;
    const int wt = blockIdx.x * 4 + wv;          // 0..1535: 32 row-tiles x 48 col-tiles
    const int rt = wt / 48, ct = wt - rt * 48;
    const int row0 = rt * 16, col0 = ct * 16;

    const float* arow = hs + (row0 + lcol) * 256;   // A: m = lcol (bs-row)
    const float* brow = Wq + (col0 + lcol) * 256;   // B: n = lcol (out-col), torch [out,in]

    floatx4 acc = {0.f, 0.f, 0.f, 0.f};
#pragma unroll
    for (int ks = 0; ks < 8; ks++) {
        const int h = ks * 32 + quad * 8;
        floatx4 a0 = *(const floatx4*)(arow + h);
        floatx4 a1 = *(const floatx4*)(arow + h + 4);
        floatx4 b0 = *(const floatx4*)(brow + h);
        floatx4 b1 = *(const floatx4*)(brow + h + 4);
        bf16x8 ahi, alo, bhi, blo;
        split8(a0, a1, ahi, alo);
        split8(b0, b1, bhi, blo);
        acc = __builtin_amdgcn_mfma_f32_16x16x32_bf16(ahi, bhi, acc, 0, 0, 0);
        acc = __builtin_amdgcn_mfma_f32_16x16x32_bf16(ahi, blo, acc, 0, 0, 0);
        acc = __builtin_amdgcn_mfma_f32_16x16x32_bf16(alo, bhi, acc, 0, 0, 0);
    }
    const float bias = bq[col0 + lcol];
    const int col = col0 + lcol, seg = col0 >> 8, jj = col & 255;
#pragma unroll
    for (int r = 0; r < 4; r++) {                   // C: row = quad*4 + r, col = lcol
        const int row = row0 + quad * 4 + r;
        const float val = acc[r] + bias;
        if (seg == 0)      q_ws[row * 256 + jj] = (f16)val;
        else if (seg == 1) k_ws[row * 256 + jj] = (f16)val;
        else               vT_ws[(row >> 8) * 65536 + jj * 256 + (row & 255)] = (f16)val;
    }
}

// ---------------- fused scores + softmax(l) + PV, v4: LDS-staged K + 16 waves/CU ----------------
// grid 512 = b(2) x sg(64: 4 s each) x pt(4: 64 p each). 512 thr = 8 waves = 4 s-slots x 2 l-halves.
// The four 64-row K-quarters are staged SEQUENTIALLY through ONE 32 KB LDS buffer (softmax partials
// accumulate additively across quarters in registers - no rescale, same math as v2/v3).
// LDS = 32K Klds + 32K Wlds + 4K merge = 68 KB -> 2 blocks/CU; acc[2][4] = 32 VGPR -> total ~100,
// launch_bounds(512,2) caps at 128 (empirical: arg=4 capped to 64 and spilled, R1 disaster).
// => 16 waves/CU AND K reads are conflict-free swizzled ds_read_b128 instead of ~200cyc L2 hits.
// K L2 traffic: 512 blocks x 128 KB = 64 MB (was 256 MB with per-wave global reads).
// T14 async stage split: next quarter's uint4s loaded into regs BEFORE the barrier, written after -
// L2 latency hides under the previous quarter's MFMAs.
__global__ __launch_bounds__(512, 2)
void attn_main(const f16* __restrict__ qw, const f16* __restrict__ kw,
               const f16* __restrict__ vT, const f16* __restrict__ Wc16,
               float* __restrict__ out)
{
    __shared__ f16 Wlds[64 * 256];      // 32768 B, XOR-swizzled (chunk c holds global chunk c^(r&7))
    __shared__ f16 Klds[64 * 256];      // 32768 B, same swizzle, restaged 4x (one K-quarter at a time)
    __shared__ float obuf[2][4][64];    //  2048 B: [lh][s-slot][p]
    __shared__ float sbuf[2][4][64];    //  2048 B

    const int bid = blockIdx.x;
    const int pt = bid & 3;
    const int sg = (bid >> 2) & 63;
    const int b  = bid >> 8;
    const int p0 = pt * 64;
    const int tid  = threadIdx.x;
    const int wv   = tid >> 6;
    const int lane = tid & 63;
    const int quad = lane >> 4, lcol = lane & 15;
    const int sslot = wv & 3, lh = wv >> 2;
    const int s = sg * 4 + sslot;

    const f16* kbase = kw + b * 65536;
    const f16* vbase = vT + b * 65536;
    const f16* qrow  = qw + (b * 256 + s) * 256;

    // ---- stage Wc tile [64 p][256 r] once, swizzled (verbatim v2 pattern) ----
#pragma unroll
    for (int it = 0; it < 4; it++) {
        const int id = it * 512 + tid;
        const int r = id >> 5, c = id & 31;
        const int csrc = c ^ (r & 7);
        *(uint4*)(Wlds + r * 256 + c * 8) =
            *(const uint4*)(Wc16 + (p0 + r) * 256 + csrc * 8);
    }

    // ---- preload K quarter 0 into registers (written to LDS inside the loop) ----
    uint4 st[4];
#pragma unroll
    for (int it = 0; it < 4; it++) {
        const int id = it * 512 + tid;
        const int r = id >> 5, csrc = (id & 31) ^ (r & 7);
        st[it] = *(const uint4*)(kbase + r * 256 + csrc * 8);
    }

    float os[4] = {0.f, 0.f, 0.f, 0.f}, ss[4] = {0.f, 0.f, 0.f, 0.f};

    for (int lq = 0; lq < 4; lq++) {
        // write staged quarter (prev-iter reads finished via end-of-loop barrier; lq=0 trivially safe)
#pragma unroll
        for (int it = 0; it < 4; it++) {
            const int id = it * 512 + tid;
            const int r = id >> 5, c = id & 31;
            *(uint4*)(Klds + r * 256 + c * 8) = st[it];
        }
        // T14: issue next quarter's loads now; they land during this quarter's compute
        if (lq < 3) {
#pragma unroll
            for (int it = 0; it < 4; it++) {
                const int id = it * 512 + tid;
                const int r = id >> 5, csrc = (id & 31) ^ (r & 7);
                st[it] = *(const uint4*)(kbase + ((lq + 1) * 64 + r) * 256 + csrc * 8);
            }
        }
        __syncthreads();   // Klds (and, at lq=0, Wlds) staged

        floatx4 acc[2][4];
#pragma unroll
        for (int i = 0; i < 2; i++)
#pragma unroll
            for (int j = 0; j < 4; j++)
                acc[i][j] = (floatx4){0.f, 0.f, 0.f, 0.f};

#pragma unroll
        for (int kk = 0; kk < 8; kk++) {
            const int rb = kk * 32 + quad * 8;
            f16x8 qv = *(const f16x8*)(qrow + rb);
            const int sw = ((kk * 4 + quad) ^ (lcol & 7)) << 3;
            f16x8 kf0 = *(const f16x8*)(Klds + (lh * 32 + lcol) * 256 + sw);
            f16x8 kf1 = *(const f16x8*)(Klds + (lh * 32 + 16 + lcol) * 256 + sw);
#pragma unroll
            for (int j = 0; j < 4; j++) {
                f16x8 w8 = *(const f16x8*)(Wlds + (j * 16 + lcol) * 256 + sw);
                f16x8 bfr = w8 * qv;
                acc[0][j] = __builtin_amdgcn_mfma_f32_16x16x32_f16(kf0, bfr, acc[0][j], 0, 0, 0);
                acc[1][j] = __builtin_amdgcn_mfma_f32_16x16x32_f16(kf1, bfr, acc[1][j], 0, 0, 0);
            }
        }

        // ---- epilogue for this quarter: P = exp(acc) f32; accumulate os/ss in regs ----
        const int lbase = lq * 64 + lh * 32;
#pragma unroll
        for (int i = 0; i < 2; i++) {
#pragma unroll
            for (int j = 0; j < 4; j++) {
                // v at (l = lbase+i*16+quad*4+t, p = p0+j*16+lcol)
                f16x4 vf = *(const f16x4*)(vbase + (p0 + j * 16 + lcol) * 256 + lbase + i * 16 + quad * 4);
#pragma unroll
                for (int t = 0; t < 4; t++) {
                    const float P = __expf(acc[i][j][t]);
                    os[j] = fmaf(P, (float)vf[t], os[j]);
                    ss[j] += P;
                }
            }
        }
        if (lq < 3) __syncthreads();   // all waves done reading Klds before restage
    }

    // ---- butterfly over quad (lanes ^16, ^32), then merge the 2 l-halves through LDS ----
#pragma unroll
    for (int j = 0; j < 4; j++) {
        os[j] += __shfl_xor(os[j], 16);
        os[j] += __shfl_xor(os[j], 32);
        ss[j] += __shfl_xor(ss[j], 16);
        ss[j] += __shfl_xor(ss[j], 32);
    }
    if (quad == 0) {
#pragma unroll
        for (int j = 0; j < 4; j++) {
            obuf[lh][sslot][j * 16 + lcol] = os[j];
            sbuf[lh][sslot][j * 16 + lcol] = ss[j];
        }
    }
    __syncthreads();

    if (tid < 256) {
        const int slot = tid >> 6, p = tid & 63;
        const float O = obuf[0][slot][p] + obuf[1][slot][p];
        const float S = sbuf[0][slot][p] + sbuf[1][slot][p];
        out[(b * 256 + sg * 4 + slot) * 256 + p0 + p] = O / S;
    }
}

extern "C" void kernel_launch(void* const* d_in, const int* in_sizes, int n_in,
                              void* d_out, int out_size, void* d_ws, size_t ws_size,
                              hipStream_t stream) {
    const float* hs   = (const float*)d_in[0];  // [2,256,256]
    const float* Wqkv = (const float*)d_in[1];  // [768,256]
    const float* bqkv = (const float*)d_in[2];  // [768]
    const float* Wc   = (const float*)d_in[3];  // [256,256]
    // d_in[4] (bc) cancels in softmax over l -> unused.
    float* out = (float*)d_out;

    char* ws = (char*)d_ws;
    f16* q_ws   = (f16*)ws;                      // 256 KB f16 q   [b*s][r]
    f16* k_ws   = (f16*)(ws + 262144);           // 256 KB f16 k   [b*l][r]
    f16* vT_ws  = (f16*)(ws + 524288);           // 256 KB f16 vT  [b][p][l]
    f16* Wc_ws  = (f16*)(ws + 786432);           // 128 KB f16 Wc  [p][r]

    proj_kernel<<<dim3(448), 256, 0, stream>>>(hs, Wqkv, bqkv, Wc, q_ws, k_ws, vT_ws, Wc_ws);
    attn_main<<<dim3(512), 512, 0, stream>>>(q_ws, k_ws, vT_ws, Wc_ws, out);
}

// Round 5
// 101.612 us; speedup vs baseline: 1.1127x; 1.1127x over previous
//
#include <hip/hip_runtime.h>
#include <hip/hip_bf16.h>
#include <math.h>

typedef __bf16 bf16;
typedef _Float16 f16;
typedef __attribute__((ext_vector_type(8))) __bf16 bf16x8;
typedef __attribute__((ext_vector_type(8))) _Float16 f16x8;
typedef __attribute__((ext_vector_type(4))) _Float16 f16x4;
typedef __attribute__((ext_vector_type(4))) float floatx4;

__device__ __forceinline__ void split8(floatx4 a0, floatx4 a1, bf16x8& hi, bf16x8& lo) {
#pragma unroll
    for (int t = 0; t < 4; t++) {
        float v0 = a0[t], v1 = a1[t];
        bf16 h0 = (bf16)v0, h1 = (bf16)v1;
        hi[t] = h0;     lo[t] = (bf16)(v0 - (float)h0);
        hi[t + 4] = h1; lo[t + 4] = (bf16)(v1 - (float)h1);
    }
}

// ---------------- projection: qkv = hs @ Wqkv^T + bqkv (fp32-accurate via bf16 hi/lo split) ----------------
// blocks 0..383: one 16x16 tile per wave -> q f16 [b*s][r], k f16 [b*l][r], vT f16 [b][p][l]
// blocks 384..447: Wc fp32 -> f16 copy (for the attn B-frag build)
__global__ __launch_bounds__(256, 4)
void proj_kernel(const float* __restrict__ hs, const float* __restrict__ Wq,
                 const float* __restrict__ bq, const float* __restrict__ Wc,
                 f16* __restrict__ q_ws, f16* __restrict__ k_ws,
                 f16* __restrict__ vT_ws, f16* __restrict__ Wc_ws)
{
    const int tid = threadIdx.x;
    if (blockIdx.x >= 384) {           // Wc fp32 -> f16
        const int base = (blockIdx.x - 384) * 1024 + tid * 4;
        floatx4 w = *(const floatx4*)(Wc + base);
        f16x4 h;
        h.x = (f16)w.x; h.y = (f16)w.y; h.z = (f16)w.z; h.w = (f16)w.w;
        *(f16x4*)(Wc_ws + base) = h;
        return;
    }
    const int wv = tid >> 6, lane = tid & 63;
    const int quad = lane >> 4, lcol = lane & 15;
    const int wt = blockIdx.x * 4 + wv;          // 0..1535: 32 row-tiles x 48 col-tiles
    const int rt = wt / 48, ct = wt - rt * 48;
    const int row0 = rt * 16, col0 = ct * 16;

    const float* arow = hs + (row0 + lcol) * 256;   // A: m = lcol (bs-row)
    const float* brow = Wq + (col0 + lcol) * 256;   // B: n = lcol (out-col), torch [out,in]

    floatx4 acc = {0.f, 0.f, 0.f, 0.f};
#pragma unroll
    for (int ks = 0; ks < 8; ks++) {
        const int h = ks * 32 + quad * 8;
        floatx4 a0 = *(const floatx4*)(arow + h);
        floatx4 a1 = *(const floatx4*)(arow + h + 4);
        floatx4 b0 = *(const floatx4*)(brow + h);
        floatx4 b1 = *(const floatx4*)(brow + h + 4);
        bf16x8 ahi, alo, bhi, blo;
        split8(a0, a1, ahi, alo);
        split8(b0, b1, bhi, blo);
        acc = __builtin_amdgcn_mfma_f32_16x16x32_bf16(ahi, bhi, acc, 0, 0, 0);
        acc = __builtin_amdgcn_mfma_f32_16x16x32_bf16(ahi, blo, acc, 0, 0, 0);
        acc = __builtin_amdgcn_mfma_f32_16x16x32_bf16(alo, bhi, acc, 0, 0, 0);
    }
    const float bias = bq[col0 + lcol];
    const int col = col0 + lcol, seg = col0 >> 8, jj = col & 255;
#pragma unroll
    for (int r = 0; r < 4; r++) {                   // C: row = quad*4 + r, col = lcol
        const int row = row0 + quad * 4 + r;
        const float val = acc[r] + bias;
        if (seg == 0)      q_ws[row * 256 + jj] = (f16)val;
        else if (seg == 1) k_ws[row * 256 + jj] = (f16)val;
        else               vT_ws[(row >> 8) * 65536 + jj * 256 + (row & 255)] = (f16)val;
    }
}

// ---------------- fused scores + softmax(l) + PV, v5: R2 structure + 2-s fusion ----------------
// grid 1024 = b(2) x sg(128: 2 s each) x pt(4: 64 p each). 512 thr = 8 waves; wave wv owns l-chunk
// [wv*32, wv*32+32) for BOTH s of the block. acc[2 s][2 i][4 j] = 64 VGPR.
// Sharing: each kf global gather (16-line scatter, the R2 latency cost) now feeds 8 MFMAs (was 4);
// w8 LDS reads and the vf/cvt epilogue are s-independent -> halved per score-element.
// LDS: Wc tile 32 KB (XOR-swizzled) + 8 KB merge = 41 KB -> 2 blocks/CU; launch_bounds(512,2) caps
// VGPR at 128 (empirical: arg=4 forced 64 and spilled catastrophically in R1).
// K from GLOBAL (L2-hot; R3 proved LDS-restaging + barriers is worse: 4 cyc/read bank conflicts +
// 10 us LDS-port occupancy + 8 barriers serialize). No barriers in the main loop.
// P = exp(scores) f32 (scores ~ N(0,1); bc cancels in softmax over l). osum/ssum per-lane FMAs +
// shfl_xor(16,32) quad-butterfly + one 8-wave LDS merge at the end (2 barriers/block total).
__global__ __launch_bounds__(512, 2)
void attn_main(const f16* __restrict__ qw, const f16* __restrict__ kw,
               const f16* __restrict__ vT, const f16* __restrict__ Wc16,
               float* __restrict__ out)
{
    __shared__ f16 Wlds[64 * 256];      // 32768 B, XOR-swizzled (chunk c holds global chunk c^(r&7))
    __shared__ float obuf[8][2][64];    //  4096 B: [wave][s][p]
    __shared__ float sbuf[8][2][64];    //  4096 B

    const int bid = blockIdx.x;
    const int pt = bid & 3;
    const int sg = (bid >> 2) & 127;
    const int b  = bid >> 9;
    const int p0 = pt * 64;
    const int tid  = threadIdx.x;
    const int wv   = tid >> 6;
    const int lane = tid & 63;
    const int quad = lane >> 4, lcol = lane & 15;
    const int l0w = wv * 32;

    const f16* kbase = kw + b * 65536;
    const f16* vbase = vT + b * 65536;
    const f16* qrow0 = qw + (b * 256 + sg * 2) * 256;
    const f16* qrow1 = qrow0 + 256;

    // ---- stage Wc tile [64 p][256 r] once, swizzled (verbatim R2 pattern) ----
#pragma unroll
    for (int it = 0; it < 4; it++) {
        const int id = it * 512 + tid;
        const int r = id >> 5, c = id & 31;
        const int csrc = c ^ (r & 7);
        *(uint4*)(Wlds + r * 256 + c * 8) =
            *(const uint4*)(Wc16 + (p0 + r) * 256 + csrc * 8);
    }
    __syncthreads();

    floatx4 acc[2][2][4];               // [s][i(l-16-chunk)][j(p-16-chunk)]
#pragma unroll
    for (int s = 0; s < 2; s++)
#pragma unroll
        for (int i = 0; i < 2; i++)
#pragma unroll
            for (int j = 0; j < 4; j++)
                acc[s][i][j] = (floatx4){0.f, 0.f, 0.f, 0.f};

#pragma unroll
    for (int kk = 0; kk < 8; kk++) {
        const int rb = kk * 32 + quad * 8;
        f16x8 qv0 = *(const f16x8*)(qrow0 + rb);                          // broadcast per quad
        f16x8 qv1 = *(const f16x8*)(qrow1 + rb);
        f16x8 kf0 = *(const f16x8*)(kbase + (l0w + lcol) * 256 + rb);     // A: m=lcol -> l-row
        f16x8 kf1 = *(const f16x8*)(kbase + (l0w + 16 + lcol) * 256 + rb);
        const int sw = ((kk * 4 + quad) ^ (lcol & 7)) << 3;
#pragma unroll
        for (int j = 0; j < 4; j++) {
            f16x8 w8 = *(const f16x8*)(Wlds + (j * 16 + lcol) * 256 + sw);
            f16x8 bf0 = w8 * qv0;       // B: n=lcol -> p-row, built in regs (pk_mul)
            f16x8 bf1 = w8 * qv1;
            acc[0][0][j] = __builtin_amdgcn_mfma_f32_16x16x32_f16(kf0, bf0, acc[0][0][j], 0, 0, 0);
            acc[0][1][j] = __builtin_amdgcn_mfma_f32_16x16x32_f16(kf1, bf0, acc[0][1][j], 0, 0, 0);
            acc[1][0][j] = __builtin_amdgcn_mfma_f32_16x16x32_f16(kf0, bf1, acc[1][0][j], 0, 0, 0);
            acc[1][1][j] = __builtin_amdgcn_mfma_f32_16x16x32_f16(kf1, bf1, acc[1][1][j], 0, 0, 0);
        }
    }

    // ---- in-register epilogue: P = exp(acc) f32; vf shared across both s ----
    float os[2][4] = {{0.f,0.f,0.f,0.f},{0.f,0.f,0.f,0.f}};
    float ss[2][4] = {{0.f,0.f,0.f,0.f},{0.f,0.f,0.f,0.f}};
#pragma unroll
    for (int i = 0; i < 2; i++) {
#pragma unroll
        for (int j = 0; j < 4; j++) {
            // v at (l = l0w+i*16+quad*4+t, p = p0+j*16+lcol)
            f16x4 vf = *(const f16x4*)(vbase + (p0 + j * 16 + lcol) * 256 + l0w + i * 16 + quad * 4);
            float vF0 = (float)vf[0], vF1 = (float)vf[1], vF2 = (float)vf[2], vF3 = (float)vf[3];
#pragma unroll
            for (int s = 0; s < 2; s++) {
                const float P0 = __expf(acc[s][i][j][0]);
                const float P1 = __expf(acc[s][i][j][1]);
                const float P2 = __expf(acc[s][i][j][2]);
                const float P3 = __expf(acc[s][i][j][3]);
                os[s][j] = fmaf(P0, vF0, os[s][j]);
                os[s][j] = fmaf(P1, vF1, os[s][j]);
                os[s][j] = fmaf(P2, vF2, os[s][j]);
                os[s][j] = fmaf(P3, vF3, os[s][j]);
                ss[s][j] += (P0 + P1) + (P2 + P3);
            }
        }
    }

    // ---- quad-butterfly (lanes ^16, ^32), then one 8-wave merge through LDS ----
#pragma unroll
    for (int s = 0; s < 2; s++)
#pragma unroll
        for (int j = 0; j < 4; j++) {
            os[s][j] += __shfl_xor(os[s][j], 16);
            os[s][j] += __shfl_xor(os[s][j], 32);
            ss[s][j] += __shfl_xor(ss[s][j], 16);
            ss[s][j] += __shfl_xor(ss[s][j], 32);
        }
    if (quad == 0) {
#pragma unroll
        for (int s = 0; s < 2; s++)
#pragma unroll
            for (int j = 0; j < 4; j++) {
                obuf[wv][s][j * 16 + lcol] = os[s][j];
                sbuf[wv][s][j * 16 + lcol] = ss[s][j];
            }
    }
    __syncthreads();

    if (tid < 128) {
        const int si = tid >> 6, p = tid & 63;
        float O = 0.f, S = 0.f;
#pragma unroll
        for (int w = 0; w < 8; w++) {
            O += obuf[w][si][p];
            S += sbuf[w][si][p];
        }
        out[(b * 256 + sg * 2 + si) * 256 + p0 + p] = O / S;
    }
}

extern "C" void kernel_launch(void* const* d_in, const int* in_sizes, int n_in,
                              void* d_out, int out_size, void* d_ws, size_t ws_size,
                              hipStream_t stream) {
    const float* hs   = (const float*)d_in[0];  // [2,256,256]
    const float* Wqkv = (const float*)d_in[1];  // [768,256]
    const float* bqkv = (const float*)d_in[2];  // [768]
    const float* Wc   = (const float*)d_in[3];  // [256,256]
    // d_in[4] (bc) cancels in softmax over l -> unused.
    float* out = (float*)d_out;

    char* ws = (char*)d_ws;
    f16* q_ws   = (f16*)ws;                      // 256 KB f16 q   [b*s][r]
    f16* k_ws   = (f16*)(ws + 262144);           // 256 KB f16 k   [b*l][r]
    f16* vT_ws  = (f16*)(ws + 524288);           // 256 KB f16 vT  [b][p][l]
    f16* Wc_ws  = (f16*)(ws + 786432);           // 128 KB f16 Wc  [p][r]

    proj_kernel<<<dim3(448), 256, 0, stream>>>(hs, Wqkv, bqkv, Wc, q_ws, k_ws, vT_ws, Wc_ws);
    attn_main<<<dim3(1024), 512, 0, stream>>>(q_ws, k_ws, vT_ws, Wc_ws, out);
}

// Round 6
// 90.279 us; speedup vs baseline: 1.2524x; 1.1255x over previous
//
#include <hip/hip_runtime.h>
#include <hip/hip_bf16.h>
#include <math.h>

typedef __bf16 bf16;
typedef _Float16 f16;
typedef __attribute__((ext_vector_type(8))) __bf16 bf16x8;
typedef __attribute__((ext_vector_type(8))) _Float16 f16x8;
typedef __attribute__((ext_vector_type(4))) _Float16 f16x4;
typedef __attribute__((ext_vector_type(4))) float floatx4;

__device__ __forceinline__ void split8(floatx4 a0, floatx4 a1, bf16x8& hi, bf16x8& lo) {
#pragma unroll
    for (int t = 0; t < 4; t++) {
        float v0 = a0[t], v1 = a1[t];
        bf16 h0 = (bf16)v0, h1 = (bf16)v1;
        hi[t] = h0;     lo[t] = (bf16)(v0 - (float)h0);
        hi[t + 4] = h1; lo[t + 4] = (bf16)(v1 - (float)h1);
    }
}

// ---------------- projection: qkv = hs @ Wqkv^T + bqkv (fp32-accurate via bf16 hi/lo split) ----------------
// blocks 0..383: one 16x16 tile per wave -> q f16 [b*s][r], k f16 [b*l][r], vT f16 [b][p][l]
// blocks 384..447: Wc fp32 -> f16 copy (for the attn B-frag build)
__global__ __launch_bounds__(256, 4)
void proj_kernel(const float* __restrict__ hs, const float* __restrict__ Wq,
                 const float* __restrict__ bq, const float* __restrict__ Wc,
                 f16* __restrict__ q_ws, f16* __restrict__ k_ws,
                 f16* __restrict__ vT_ws, f16* __restrict__ Wc_ws)
{
    const int tid = threadIdx.x;
    if (blockIdx.x >= 384) {           // Wc fp32 -> f16
        const int base = (blockIdx.x - 384) * 1024 + tid * 4;
        floatx4 w = *(const floatx4*)(Wc + base);
        f16x4 h;
        h.x = (f16)w.x; h.y = (f16)w.y; h.z = (f16)w.z; h.w = (f16)w.w;
        *(f16x4*)(Wc_ws + base) = h;
        return;
    }
    const int wv = tid >> 6, lane = tid & 63;
    const int quad = lane >> 4, lcol = lane & 15;
    const int wt = blockIdx.x * 4 + wv;          // 0..1535: 32 row-tiles x 48 col-tiles
    const int rt = wt / 48, ct = wt - rt * 48;
    const int row0 = rt * 16, col0 = ct * 16;

    const float* arow = hs + (row0 + lcol) * 256;   // A: m = lcol (bs-row)
    const float* brow = Wq + (col0 + lcol) * 256;   // B: n = lcol (out-col), torch [out,in]

    floatx4 acc = {0.f, 0.f, 0.f, 0.f};
#pragma unroll
    for (int ks = 0; ks < 8; ks++) {
        const int h = ks * 32 + quad * 8;
        floatx4 a0 = *(const floatx4*)(arow + h);
        floatx4 a1 = *(const floatx4*)(arow + h + 4);
        floatx4 b0 = *(const floatx4*)(brow + h);
        floatx4 b1 = *(const floatx4*)(brow + h + 4);
        bf16x8 ahi, alo, bhi, blo;
        split8(a0, a1, ahi, alo);
        split8(b0, b1, bhi, blo);
        acc = __builtin_amdgcn_mfma_f32_16x16x32_bf16(ahi, bhi, acc, 0, 0, 0);
        acc = __builtin_amdgcn_mfma_f32_16x16x32_bf16(ahi, blo, acc, 0, 0, 0);
        acc = __builtin_amdgcn_mfma_f32_16x16x32_bf16(alo, bhi, acc, 0, 0, 0);
    }
    const float bias = bq[col0 + lcol];
    const int col = col0 + lcol, seg = col0 >> 8, jj = col & 255;
#pragma unroll
    for (int r = 0; r < 4; r++) {                   // C: row = quad*4 + r, col = lcol
        const int row = row0 + quad * 4 + r;
        const float val = acc[r] + bias;
        if (seg == 0)      q_ws[row * 256 + jj] = (f16)val;
        else if (seg == 1) k_ws[row * 256 + jj] = (f16)val;
        else               vT_ws[(row >> 8) * 65536 + jj * 256 + (row & 255)] = (f16)val;
    }
}

// ---------------- v6: partial-l attention. Block = (b, lq, pt, 8 s). Wave = 1 s x 64 l x 64 p. ----------------
// grid 1024 = b(2) x sg(32) x lq(4) x pt(4). 512 thr = 8 waves = 8 distinct s-values.
// Rationale (R5 post-mortem): halving operand traffic was NEUTRAL -> not load-bound; all pipes <25%,
// per-wave chain (load->pk_mul->MFMA->exp->fma) serializes. This version:
//  - each wave owns a DISTINCT s -> the q*Wc pk_mul B-frag build is no longer 8x redundant per block
//  - K-quarter + Wc + vT-tile staged ONCE (one barrier total; R3's restage-per-quarter is what lost)
//  - all inner-loop + epilogue operands LDS-local (short lgkm waits, fine-grained by compiler)
//  - softmax over l split across lq blocks: partial os/ss -> workspace, merged by a tiny 3rd kernel
//    (exp is monotone-safe: scores ~ N(0,1), no max-sub needed, partials add)
// LDS: Klds 32K (XOR-swizzle, R3-verified pattern) + Wlds 32K + vTlds [64][68] pad 8.5K = 74 KB
// -> 2 blocks/CU; acc[4][4]=64 VGPR, total ~110 under the (512,2)=128 cap -> 16 waves/CU.
__global__ __launch_bounds__(512, 2)
void attn_partial(const f16* __restrict__ qw, const f16* __restrict__ kw,
                  const f16* __restrict__ vT, const f16* __restrict__ Wc16,
                  float* __restrict__ osum_ws, float* __restrict__ ssum_ws)
{
    __shared__ f16 Klds[64 * 256];      // 32768 B  rows l = lq*64 + r, chunk c holds global chunk c^(r&7)
    __shared__ f16 Wlds[64 * 256];      // 32768 B  rows p = p0 + r, same swizzle
    __shared__ f16 vTlds[64 * 68];      //  8704 B  [p][l] pad-68: b64 reads 2-way max (free)

    const int bid = blockIdx.x;
    const int pt = bid & 3;
    const int lq = (bid >> 2) & 3;
    const int sg = (bid >> 4) & 31;
    const int b  = bid >> 9;
    const int p0 = pt * 64;
    const int l0 = lq * 64;
    const int tid  = threadIdx.x;
    const int wv   = tid >> 6;
    const int lane = tid & 63;
    const int quad = lane >> 4, lcol = lane & 15;
    const int s = sg * 8 + wv;          // each wave: one distinct s

    const f16* kbase = kw + b * 65536;
    const f16* vbase = vT + b * 65536;
    const f16* qrow  = qw + (b * 256 + s) * 256;

    // ---- stage K-quarter [64 l][256 r], swizzled (R3-verified pattern) ----
#pragma unroll
    for (int it = 0; it < 4; it++) {
        const int id = it * 512 + tid;
        const int r = id >> 5, c = id & 31;
        const int csrc = c ^ (r & 7);
        *(uint4*)(Klds + r * 256 + c * 8) =
            *(const uint4*)(kbase + (l0 + r) * 256 + csrc * 8);
    }
    // ---- stage Wc tile [64 p][256 r], swizzled (R2-verified pattern) ----
#pragma unroll
    for (int it = 0; it < 4; it++) {
        const int id = it * 512 + tid;
        const int r = id >> 5, c = id & 31;
        const int csrc = c ^ (r & 7);
        *(uint4*)(Wlds + r * 256 + c * 8) =
            *(const uint4*)(Wc16 + (p0 + r) * 256 + csrc * 8);
    }
    // ---- stage vT tile [64 p][64 l] into pad-68 rows (b64-grain, aligned) ----
#pragma unroll
    for (int it = 0; it < 2; it++) {
        const int id = it * 512 + tid;      // 1024 f16x4 chunks
        const int p = id >> 4, c = id & 15;
        *(f16x4*)(vTlds + p * 68 + c * 4) =
            *(const f16x4*)(vbase + (p0 + p) * 256 + l0 + c * 4);
    }
    __syncthreads();                        // the ONLY barrier

    floatx4 acc[4][4];                      // [i: l-16-chunk][j: p-16-chunk]
#pragma unroll
    for (int i = 0; i < 4; i++)
#pragma unroll
        for (int j = 0; j < 4; j++)
            acc[i][j] = (floatx4){0.f, 0.f, 0.f, 0.f};

#pragma unroll
    for (int kk = 0; kk < 8; kk++) {
        const int rb = kk * 32 + quad * 8;
        f16x8 qv = *(const f16x8*)(qrow + rb);                  // 64B line, L1-hot
        const int sw = ((kk * 4 + quad) ^ (lcol & 7)) << 3;     // swizzled k-chunk
        f16x8 kf[4];
#pragma unroll
        for (int i = 0; i < 4; i++)         // A-frag from LDS: m = lcol -> l-row (2-way = free)
            kf[i] = *(const f16x8*)(Klds + (i * 16 + lcol) * 256 + sw);
#pragma unroll
        for (int j = 0; j < 4; j++) {       // B-frag: n = lcol -> p-row; unique per wave (unique s)
            f16x8 w8 = *(const f16x8*)(Wlds + (j * 16 + lcol) * 256 + sw);
            f16x8 bfr = w8 * qv;
#pragma unroll
            for (int i = 0; i < 4; i++)
                acc[i][j] = __builtin_amdgcn_mfma_f32_16x16x32_f16(kf[i], bfr, acc[i][j], 0, 0, 0);
        }
    }

    // ---- epilogue: P = exp(acc) f32; vf from vTlds (b64, conflict-light); partial os/ss ----
    float os[4] = {0.f, 0.f, 0.f, 0.f}, ss[4] = {0.f, 0.f, 0.f, 0.f};
#pragma unroll
    for (int i = 0; i < 4; i++) {
#pragma unroll
        for (int j = 0; j < 4; j++) {
            // v at (p = p0+j*16+lcol, l = l0+i*16+quad*4+t), local [p][l] pad-68
            f16x4 vf = *(const f16x4*)(vTlds + (j * 16 + lcol) * 68 + i * 16 + quad * 4);
#pragma unroll
            for (int t = 0; t < 4; t++) {
                const float P = __expf(acc[i][j][t]);
                os[j] = fmaf(P, (float)vf[t], os[j]);
                ss[j] += P;
            }
        }
    }

    // ---- quad-butterfly; write partial (s, 64p) for this lq to workspace ----
#pragma unroll
    for (int j = 0; j < 4; j++) {
        os[j] += __shfl_xor(os[j], 16);
        os[j] += __shfl_xor(os[j], 32);
        ss[j] += __shfl_xor(ss[j], 16);
        ss[j] += __shfl_xor(ss[j], 32);
    }
    if (quad == 0) {
        const int base = ((b * 256 + s) * 4 + lq) * 256 + p0;
#pragma unroll
        for (int j = 0; j < 4; j++) {
            osum_ws[base + j * 16 + lcol] = os[j];
            ssum_ws[base + j * 16 + lcol] = ss[j];
        }
    }
}

// ---------------- v6 merge: out[b,s,p] = sum_lq os / sum_lq ss ----------------
__global__ __launch_bounds__(256, 4)
void merge_kernel(const float* __restrict__ osum_ws, const float* __restrict__ ssum_ws,
                  float* __restrict__ out)
{
    const int g = blockIdx.x * 256 + threadIdx.x;   // 131072 outputs
    const int p = g & 255, bs = g >> 8;
    const int base = bs * 1024 + p;
    float O = 0.f, S = 0.f;
#pragma unroll
    for (int lq = 0; lq < 4; lq++) {
        O += osum_ws[base + lq * 256];
        S += ssum_ws[base + lq * 256];
    }
    out[g] = O / S;
}

extern "C" void kernel_launch(void* const* d_in, const int* in_sizes, int n_in,
                              void* d_out, int out_size, void* d_ws, size_t ws_size,
                              hipStream_t stream) {
    const float* hs   = (const float*)d_in[0];  // [2,256,256]
    const float* Wqkv = (const float*)d_in[1];  // [768,256]
    const float* bqkv = (const float*)d_in[2];  // [768]
    const float* Wc   = (const float*)d_in[3];  // [256,256]
    // d_in[4] (bc) cancels in softmax over l -> unused.
    float* out = (float*)d_out;

    char* ws = (char*)d_ws;
    f16* q_ws   = (f16*)ws;                      // 256 KB f16 q   [b*s][r]
    f16* k_ws   = (f16*)(ws + 262144);           // 256 KB f16 k   [b*l][r]
    f16* vT_ws  = (f16*)(ws + 524288);           // 256 KB f16 vT  [b][p][l]
    f16* Wc_ws  = (f16*)(ws + 786432);           // 128 KB f16 Wc  [p][r]
    float* osum_ws = (float*)(ws + 1048576);     // 2 MB f32 [b][s][lq][p]
    float* ssum_ws = (float*)(ws + 3145728);     // 2 MB f32 [b][s][lq][p]

    proj_kernel<<<dim3(448), 256, 0, stream>>>(hs, Wqkv, bqkv, Wc, q_ws, k_ws, vT_ws, Wc_ws);
    attn_partial<<<dim3(1024), 512, 0, stream>>>(q_ws, k_ws, vT_ws, Wc_ws, osum_ws, ssum_ws);
    merge_kernel<<<dim3(512), 256, 0, stream>>>(osum_ws, ssum_ws, out);
}